// Round 1
// baseline (711.910 us; speedup 1.0000x reference)
//
#include <hip/hip_runtime.h>
#include <stdint.h>

typedef float f32x4 __attribute__((ext_vector_type(4)));
typedef __bf16 bf16x8 __attribute__((ext_vector_type(8)));
typedef unsigned short u16;
typedef unsigned short u16x8 __attribute__((ext_vector_type(8)));

__device__ __forceinline__ u16 f2b(float f) {
    union { float f; unsigned u; } v; v.f = f;
    return (u16)((v.u + 0x7fffu + ((v.u >> 16) & 1u)) >> 16);
}
__device__ __forceinline__ float b2f(u16 b) {
    union { unsigned u; float f; } v; v.u = ((unsigned)b) << 16;
    return v.f;
}

// ---------------- cast fp32 -> bf16 (8 elems/thread) ----------------
__global__ __launch_bounds__(256) void k_cast(const float* __restrict__ src, u16* __restrict__ dst, int n) {
    int i = (blockIdx.x * 256 + threadIdx.x) * 8;
    if (i >= n) return;
    const float4* s = (const float4*)(src + i);
    float4 a = s[0], b = s[1];
    u16x8 o;
    o[0] = f2b(a.x); o[1] = f2b(a.y); o[2] = f2b(a.z); o[3] = f2b(a.w);
    o[4] = f2b(b.x); o[5] = f2b(b.y); o[6] = f2b(b.z); o[7] = f2b(b.w);
    *(u16x8*)(dst + i) = o;
}

// ---------------- transpose + cast: src[R][C] f32 -> dst[C][R] bf16 ----------------
__global__ __launch_bounds__(256) void k_transpose(const float* __restrict__ src, u16* __restrict__ dst,
                                                   int R, int C) {
    __shared__ float tile[64][65];
    int c0 = blockIdx.x * 64, r0 = blockIdx.y * 64;
    int tx = threadIdx.x & 63, ty = threadIdx.x >> 6;
    #pragma unroll
    for (int r = ty; r < 64; r += 4)
        tile[r][tx] = src[(size_t)(r0 + r) * C + (c0 + tx)];
    __syncthreads();
    #pragma unroll
    for (int r = ty; r < 64; r += 4)
        dst[(size_t)(c0 + r) * R + (r0 + tx)] = f2b(tile[tx][r]);
}

// ---------------- GEMM core: C[m][n] = sum_k A[m][k] * Bt[n][k], bf16 in, tile 128x128, BK=64 ----------------
// 4 waves, each computes a 64x64 sub-tile as 4x4 mfma_16x16x32 fragments.
// A-frag: lane holds A[row=l&15][k=(l>>4)*8 + j]; B-frag: lane holds B[k][col=l&15] = Bt[col][k].
// C/D: lane l reg e -> row=(l>>4)*4+e, col=l&15  (m89-verified layout).
template <typename OutT>
__device__ __forceinline__ void gemm_core(const u16* __restrict__ A, const u16* __restrict__ Bt,
                                          OutT* __restrict__ C, int K, int ldc, int m0, int n0) {
    __shared__ u16 Al[128][72];   // +8 pad: row stride 144B -> 2-way (free) bank pattern
    __shared__ u16 Bl[128][72];
    int t = threadIdx.x;
    int l = t & 63, w = t >> 6;
    int wr = (w >> 1) * 64, wc = (w & 1) * 64;
    int lr = l & 15, lk = (l >> 4) * 8;
    f32x4 acc[4][4] = {};
    for (int k0 = 0; k0 < K; k0 += 64) {
        __syncthreads();
        #pragma unroll
        for (int c = 0; c < 4; ++c) {
            int idx = c * 256 + t;          // 1024 chunks of 8 bf16
            int row = idx >> 3, seg = (idx & 7) * 8;
            *(bf16x8*)&Al[row][seg] = *(const bf16x8*)(A + (size_t)(m0 + row) * K + (k0 + seg));
            *(bf16x8*)&Bl[row][seg] = *(const bf16x8*)(Bt + (size_t)(n0 + row) * K + (k0 + seg));
        }
        __syncthreads();
        #pragma unroll
        for (int kk = 0; kk < 64; kk += 32) {
            bf16x8 af[4], bfr[4];
            #pragma unroll
            for (int i = 0; i < 4; ++i) {
                af[i]  = *(const bf16x8*)&Al[wr + i * 16 + lr][kk + lk];
                bfr[i] = *(const bf16x8*)&Bl[wc + i * 16 + lr][kk + lk];
            }
            #pragma unroll
            for (int i = 0; i < 4; ++i)
                #pragma unroll
                for (int j = 0; j < 4; ++j)
                    acc[i][j] = __builtin_amdgcn_mfma_f32_16x16x32_bf16(af[i], bfr[j], acc[i][j], 0, 0, 0);
        }
    }
    int li = (l >> 4) * 4;
    #pragma unroll
    for (int i = 0; i < 4; ++i)
        #pragma unroll
        for (int j = 0; j < 4; ++j)
            #pragma unroll
            for (int e = 0; e < 4; ++e) {
                int row = m0 + wr + i * 16 + li + e;
                int col = n0 + wc + j * 16 + lr;
                if constexpr (sizeof(OutT) == 4)
                    C[(size_t)row * ldc + col] = acc[i][j][e];
                else
                    C[(size_t)row * ldc + col] = f2b(acc[i][j][e]);
            }
}

// QKV fused over concatenated N: nt 0..31 -> Q, 32..39 -> K, 40..47 -> V
__global__ __launch_bounds__(256) void k_gemm_qkv(const u16* __restrict__ hsb,
        const u16* __restrict__ WqT, const u16* __restrict__ WkT, const u16* __restrict__ WvT,
        u16* __restrict__ Qb, u16* __restrict__ Kb, u16* __restrict__ Vb) {
    int nt = blockIdx.x, mt = blockIdx.y;
    const u16* Bt; u16* C; int ldc, n0;
    if (nt < 32)      { Bt = WqT; C = Qb; ldc = 4096; n0 = nt * 128; }
    else if (nt < 40) { Bt = WkT; C = Kb; ldc = 1024; n0 = (nt - 32) * 128; }
    else              { Bt = WvT; C = Vb; ldc = 1024; n0 = (nt - 40) * 128; }
    gemm_core<u16>(hsb, Bt, C, 4096, ldc, mt * 128, n0);
}

__global__ __launch_bounds__(256) void k_gemm_out(const u16* __restrict__ Ob, const u16* __restrict__ WoT,
                                                  float* __restrict__ out) {
    gemm_core<float>(Ob, WoT, out, 4096, 4096, blockIdx.y * 128, blockIdx.x * 128);
}

// ---------------- RoPE in-place on Q (32 heads) and K (8 heads) ----------------
__global__ __launch_bounds__(256) void k_rope(u16* __restrict__ Qb, u16* __restrict__ Kb) {
    int t = blockIdx.x * 256 + threadIdx.x;
    int i = t & 63;
    int rest = t >> 6;
    int head = rest % 40;
    int s = rest / 40;
    if (s >= 2048) return;
    u16* base = (head < 32) ? (Qb + (size_t)s * 4096 + head * 128)
                            : (Kb + (size_t)s * 1024 + (head - 32) * 128);
    // inv_freq = 10000^(-i/64) = exp2(-i/64 * log2(10000))
    float inv = exp2f((float)i * (-13.287712379549449f / 64.0f));
    float fr = (float)s * inv;
    float sn, cs;
    sincosf(fr, &sn, &cs);
    float x1 = b2f(base[i]), x2 = b2f(base[i + 64]);
    base[i]      = f2b(x1 * cs - x2 * sn);
    base[i + 64] = f2b(x2 * cs + x1 * sn);
}

// ---------------- Flash attention, causal, GQA 32/8, Dh=128 ----------------
// Block: 256 thr = 4 waves; block handles head h, q rows [q0, q0+64); wave w rows q0+16w..+16.
// KVBLK=64. exp base-2 with c = log2(e)/sqrt(128) folded in.
__global__ __launch_bounds__(256) void k_attn(const u16* __restrict__ Q, const u16* __restrict__ K,
                                              const u16* __restrict__ V, u16* __restrict__ O) {
    __shared__ u16 Kl[64][136];    // [kv][d], +8 pad (272B stride)
    __shared__ u16 Vt[128][72];    // [d][kv], +8 pad
    __shared__ u16 Pl[4][16][72];  // per-wave P tile [qrow16][kv64], +8 pad
    int bid = blockIdx.x;
    int h = bid >> 5, qb = bid & 31;
    int kh = h >> 2;
    int q0 = qb * 64;
    int t = threadIdx.x, l = t & 63, w = t >> 6;
    int lr = l & 15, lg = l >> 4;
    const float cexp = 0.12751742f;  // log2(e)/sqrt(128)

    bf16x8 qf[4];
    {
        size_t qoff = (size_t)(q0 + w * 16 + lr) * 4096 + h * 128 + lg * 8;
        #pragma unroll
        for (int d = 0; d < 4; ++d)
            qf[d] = *(const bf16x8*)(Q + qoff + d * 32);
    }
    f32x4 oacc[8] = {};
    float mrow[4] = {-3.0e38f, -3.0e38f, -3.0e38f, -3.0e38f};
    float lrow[4] = {0.f, 0.f, 0.f, 0.f};

    int nkv = qb + 1;
    for (int kt = 0; kt < nkv; ++kt) {
        int kv0 = kt * 64;
        __syncthreads();
        #pragma unroll
        for (int c = 0; c < 4; ++c) {
            int idx = c * 256 + t;          // 1024 chunks of 8
            int r = idx >> 4, sg = (idx & 15) * 8;
            size_t goff = (size_t)(kv0 + r) * 1024 + kh * 128 + sg;
            *(bf16x8*)&Kl[r][sg] = *(const bf16x8*)(K + goff);
            u16 vv[8];
            *(bf16x8*)vv = *(const bf16x8*)(V + goff);
            #pragma unroll
            for (int j = 0; j < 8; ++j)
                Vt[sg + j][r] = vv[j];      // transpose-on-write
        }
        __syncthreads();

        // S = Q K^T  (raw, scale folded into exp)
        f32x4 sacc[4] = {};
        #pragma unroll
        for (int cb = 0; cb < 4; ++cb)
            #pragma unroll
            for (int d = 0; d < 4; ++d) {
                bf16x8 kf = *(const bf16x8*)&Kl[cb * 16 + lr][d * 32 + lg * 8];
                sacc[cb] = __builtin_amdgcn_mfma_f32_16x16x32_bf16(qf[d], kf, sacc[cb], 0, 0, 0);
            }
        // causal mask: only the diagonal tile needs it
        if (kt == nkv - 1) {
            #pragma unroll
            for (int cb = 0; cb < 4; ++cb)
                #pragma unroll
                for (int e = 0; e < 4; ++e) {
                    int row = q0 + w * 16 + lg * 4 + e;
                    int col = kv0 + cb * 16 + lr;
                    if (col > row) sacc[cb][e] = -3.0e38f;
                }
        }
        // online softmax per row (row = lg*4+e within wave; 16-lane col groups)
        #pragma unroll
        for (int e = 0; e < 4; ++e) {
            float v = fmaxf(fmaxf(sacc[0][e], sacc[1][e]), fmaxf(sacc[2][e], sacc[3][e]));
            v = fmaxf(v, __shfl_xor(v, 1));
            v = fmaxf(v, __shfl_xor(v, 2));
            v = fmaxf(v, __shfl_xor(v, 4));
            v = fmaxf(v, __shfl_xor(v, 8));
            float mnew = fmaxf(mrow[e], v);
            float alpha = exp2f((mrow[e] - mnew) * cexp);
            mrow[e] = mnew;
            float s = 0.f;
            #pragma unroll
            for (int cb = 0; cb < 4; ++cb) {
                float p = exp2f((sacc[cb][e] - mnew) * cexp);
                sacc[cb][e] = p;
                s += p;
            }
            s += __shfl_xor(s, 1);
            s += __shfl_xor(s, 2);
            s += __shfl_xor(s, 4);
            s += __shfl_xor(s, 8);
            lrow[e] = lrow[e] * alpha + s;
            #pragma unroll
            for (int db = 0; db < 8; ++db) oacc[db][e] *= alpha;
        }
        // P -> per-wave LDS (bf16), then PV
        #pragma unroll
        for (int cb = 0; cb < 4; ++cb)
            #pragma unroll
            for (int e = 0; e < 4; ++e)
                Pl[w][lg * 4 + e][cb * 16 + lr] = f2b(sacc[cb][e]);
        asm volatile("s_waitcnt lgkmcnt(0)" ::: "memory");  // wave-internal write->read ordering
        #pragma unroll
        for (int ks = 0; ks < 2; ++ks) {
            bf16x8 pf = *(const bf16x8*)&Pl[w][lr][ks * 32 + lg * 8];
            #pragma unroll
            for (int db = 0; db < 8; ++db) {
                bf16x8 vf = *(const bf16x8*)&Vt[db * 16 + lr][ks * 32 + lg * 8];
                oacc[db] = __builtin_amdgcn_mfma_f32_16x16x32_bf16(pf, vf, oacc[db], 0, 0, 0);
            }
        }
    }
    #pragma unroll
    for (int db = 0; db < 8; ++db)
        #pragma unroll
        for (int e = 0; e < 4; ++e) {
            int row = q0 + w * 16 + lg * 4 + e;
            O[(size_t)row * 4096 + h * 128 + db * 16 + lr] = f2b(oacc[db][e] / lrow[e]);
        }
}

extern "C" void kernel_launch(void* const* d_in, const int* in_sizes, int n_in,
                              void* d_out, int out_size, void* d_ws, size_t ws_size,
                              hipStream_t stream) {
    const float* hs = (const float*)d_in[0];
    const float* Wq = (const float*)d_in[1];
    const float* Wk = (const float*)d_in[2];
    const float* Wv = (const float*)d_in[3];
    const float* Wo = (const float*)d_in[4];
    float* out = (float*)d_out;
    char* ws = (char*)d_ws;
    // workspace layout (peak 88 MiB, with aliasing)
    u16* hsb = (u16*)(ws);              // 2048x4096 bf16 (16.78MB); later reused as Ob
    u16* WqT = (u16*)(ws + 16777216);   // 4096x4096 (33.55MB);      later reused as WoT
    u16* WkT = (u16*)(ws + 50331648);   // 1024x4096 (8.39MB)
    u16* WvT = (u16*)(ws + 58720256);   // 1024x4096 (8.39MB)
    u16* Qb  = (u16*)(ws + 67108864);   // 2048x4096 (16.78MB)
    u16* Kb  = (u16*)(ws + 83886080);   // 2048x1024 (4.19MB)
    u16* Vb  = (u16*)(ws + 88080384);   // 2048x1024 (4.19MB)  -> end 92274688

    k_cast<<<4096, 256, 0, stream>>>(hs, hsb, 2048 * 4096);
    k_transpose<<<dim3(64, 64), 256, 0, stream>>>(Wq, WqT, 4096, 4096);
    k_transpose<<<dim3(16, 64), 256, 0, stream>>>(Wk, WkT, 4096, 1024);
    k_transpose<<<dim3(16, 64), 256, 0, stream>>>(Wv, WvT, 4096, 1024);
    k_gemm_qkv<<<dim3(48, 16), 256, 0, stream>>>(hsb, WqT, WkT, WvT, Qb, Kb, Vb);
    k_rope<<<20480, 256, 0, stream>>>(Qb, Kb);
    u16* Ob = hsb;  // hsb dead after QKV gemm
    k_attn<<<1024, 256, 0, stream>>>(Qb, Kb, Vb, Ob);
    u16* WoT = WqT; // WqT dead after QKV gemm
    k_transpose<<<dim3(64, 64), 256, 0, stream>>>(Wo, WoT, 4096, 4096);
    k_gemm_out<<<dim3(32, 16), 256, 0, stream>>>(Ob, WoT, out);
}

// Round 2
// 483.551 us; speedup vs baseline: 1.4723x; 1.4723x over previous
//
#include <hip/hip_runtime.h>
#include <stdint.h>

typedef float f32x4 __attribute__((ext_vector_type(4)));
typedef __bf16 bf16x8 __attribute__((ext_vector_type(8)));
typedef unsigned short u16;
typedef unsigned short u16x8 __attribute__((ext_vector_type(8)));

__device__ __forceinline__ u16 f2b(float f) {
    union { float f; unsigned u; } v; v.f = f;
    return (u16)((v.u + 0x7fffu + ((v.u >> 16) & 1u)) >> 16);
}
__device__ __forceinline__ float b2f(u16 b) {
    union { unsigned u; float f; } v; v.u = ((unsigned)b) << 16;
    return v.f;
}

__device__ __forceinline__ void gload16(const u16* g, u16* s) {
    __builtin_amdgcn_global_load_lds((const __attribute__((address_space(1))) void*)g,
                                     (__attribute__((address_space(3))) void*)s, 16, 0, 0);
}

// ---------------- cast fp32 -> bf16 (8 elems/thread) ----------------
__global__ __launch_bounds__(256) void k_cast(const float* __restrict__ src, u16* __restrict__ dst, int n) {
    int i = (blockIdx.x * 256 + threadIdx.x) * 8;
    if (i >= n) return;
    const float4* s = (const float4*)(src + i);
    float4 a = s[0], b = s[1];
    u16x8 o;
    o[0] = f2b(a.x); o[1] = f2b(a.y); o[2] = f2b(a.z); o[3] = f2b(a.w);
    o[4] = f2b(b.x); o[5] = f2b(b.y); o[6] = f2b(b.z); o[7] = f2b(b.w);
    *(u16x8*)(dst + i) = o;
}

// ---------------- transpose + cast: src[R][C] f32 -> dst[C][R] bf16 ----------------
__global__ __launch_bounds__(256) void k_transpose(const float* __restrict__ src, u16* __restrict__ dst,
                                                   int R, int C) {
    __shared__ float tile[64][65];
    int c0 = blockIdx.x * 64, r0 = blockIdx.y * 64;
    int tx = threadIdx.x & 63, ty = threadIdx.x >> 6;
    #pragma unroll
    for (int r = ty; r < 64; r += 4)
        tile[r][tx] = src[(size_t)(r0 + r) * C + (c0 + tx)];
    __syncthreads();
    #pragma unroll
    for (int r = ty; r < 64; r += 4)
        dst[(size_t)(c0 + r) * R + (r0 + tx)] = f2b(tile[tx][r]);
}

// ---------------- GEMM core (m97 structure): 128x128 tile, BK=64, global_load_lds staging ----------------
template <typename OutT>
__device__ __forceinline__ void gemm_core(const u16* __restrict__ A, const u16* __restrict__ Bt,
                                          OutT* __restrict__ C, int K, int ldc, int m0, int n0) {
    __shared__ u16 Al[128][64];
    __shared__ u16 Bl[128][64];
    int t = threadIdx.x;
    int l = t & 63, w = t >> 6;
    int wr = (w >> 1) * 64, wc = (w & 1) * 64;
    int lr = l & 15, lk = (l >> 4) * 8;
    int srow = l >> 3;          // 0..7 within 8-row chunk
    int skk  = (l & 7) * 8;     // k offset within row
    f32x4 acc[4][4] = {};
    for (int k0 = 0; k0 < K; k0 += 64) {
        __syncthreads();
        #pragma unroll
        for (int c = 0; c < 4; ++c) {
            int r0 = w * 32 + c * 8;
            gload16(A  + (size_t)(m0 + r0 + srow) * K + k0 + skk, &Al[r0][0]);
            gload16(Bt + (size_t)(n0 + r0 + srow) * K + k0 + skk, &Bl[r0][0]);
        }
        __syncthreads();
        #pragma unroll
        for (int kk = 0; kk < 64; kk += 32) {
            bf16x8 af[4], bfr[4];
            #pragma unroll
            for (int i = 0; i < 4; ++i) {
                af[i]  = *(const bf16x8*)&Al[wr + i * 16 + lr][kk + lk];
                bfr[i] = *(const bf16x8*)&Bl[wc + i * 16 + lr][kk + lk];
            }
            #pragma unroll
            for (int i = 0; i < 4; ++i)
                #pragma unroll
                for (int j = 0; j < 4; ++j)
                    acc[i][j] = __builtin_amdgcn_mfma_f32_16x16x32_bf16(af[i], bfr[j], acc[i][j], 0, 0, 0);
        }
    }
    int li = (l >> 4) * 4;
    #pragma unroll
    for (int i = 0; i < 4; ++i)
        #pragma unroll
        for (int j = 0; j < 4; ++j)
            #pragma unroll
            for (int e = 0; e < 4; ++e) {
                int row = m0 + wr + i * 16 + li + e;
                int col = n0 + wc + j * 16 + lr;
                if constexpr (sizeof(OutT) == 4)
                    C[(size_t)row * ldc + col] = acc[i][j][e];
                else
                    C[(size_t)row * ldc + col] = f2b(acc[i][j][e]);
            }
}

__global__ __launch_bounds__(256) void k_gemm_qkv(const u16* __restrict__ hsb,
        const u16* __restrict__ WqT, const u16* __restrict__ WkT, const u16* __restrict__ WvT,
        u16* __restrict__ Qb, u16* __restrict__ Kb, u16* __restrict__ Vb) {
    int nt = blockIdx.x, mt = blockIdx.y;
    const u16* Bt; u16* C; int ldc, n0;
    if (nt < 32)      { Bt = WqT; C = Qb; ldc = 4096; n0 = nt * 128; }
    else if (nt < 40) { Bt = WkT; C = Kb; ldc = 1024; n0 = (nt - 32) * 128; }
    else              { Bt = WvT; C = Vb; ldc = 1024; n0 = (nt - 40) * 128; }
    gemm_core<u16>(hsb, Bt, C, 4096, ldc, mt * 128, n0);
}

__global__ __launch_bounds__(256) void k_gemm_out(const u16* __restrict__ Ob, const u16* __restrict__ WoT,
                                                  float* __restrict__ out) {
    gemm_core<float>(Ob, WoT, out, 4096, 4096, blockIdx.y * 128, blockIdx.x * 128);
}

// ---------------- RoPE in-place on Q (32 heads) and K (8 heads) ----------------
__global__ __launch_bounds__(256) void k_rope(u16* __restrict__ Qb, u16* __restrict__ Kb) {
    int t = blockIdx.x * 256 + threadIdx.x;
    int i = t & 63;
    int rest = t >> 6;
    int head = rest % 40;
    int s = rest / 40;
    if (s >= 2048) return;
    u16* base = (head < 32) ? (Qb + (size_t)s * 4096 + head * 128)
                            : (Kb + (size_t)s * 1024 + (head - 32) * 128);
    float inv = exp2f((float)i * (-13.287712379549449f / 64.0f));
    float fr = (float)s * inv;
    float sn, cs;
    sincosf(fr, &sn, &cs);
    float x1 = b2f(base[i]), x2 = b2f(base[i + 64]);
    base[i]      = f2b(x1 * cs - x2 * sn);
    base[i + 64] = f2b(x2 * cs + x1 * sn);
}

// ---------------- Flash attention, causal, GQA 32/8, Dh=128 ----------------
// QBLK=128: 4 waves x 32 q-rows (2 row-blocks of 16). KVBLK=64.
// grid 512 = 32 heads x 16 qb; qb = j<8 ? j : 23-j so bid/bid+256 are complementary (CU balance).
// T14 async staging: global->reg issued right after staging barrier, reg->LDS next iteration.
// Vt columns XOR-swizzled at 8-elem granularity: phys group = (kv>>3) ^ ((d>>3)&7).
__global__ __launch_bounds__(256, 2) void k_attn(const u16* __restrict__ Q, const u16* __restrict__ K,
                                                 const u16* __restrict__ V, u16* __restrict__ O) {
    __shared__ u16 Kl[64][136];    // [kv][d], +8 pad
    __shared__ u16 Vt[128][72];    // [d][kv swizzled], +8 pad
    __shared__ u16 Pl[4][32][72];  // per-wave P [qrow32][kv64], +8 pad
    int bid = blockIdx.x;
    int h = bid & 31;
    int j = bid >> 5;
    int qb = (j < 8) ? j : 23 - j;
    int kh = h >> 2;
    int q0 = qb * 128;
    int t = threadIdx.x, l = t & 63, w = t >> 6;
    int lr = l & 15, lg = l >> 4;
    const float cexp = 0.12751742f;  // log2(e)/sqrt(128)

    bf16x8 qf[2][4];
    #pragma unroll
    for (int rb = 0; rb < 2; ++rb) {
        size_t qoff = (size_t)(q0 + w * 32 + rb * 16 + lr) * 4096 + h * 128 + lg * 8;
        #pragma unroll
        for (int d = 0; d < 4; ++d)
            qf[rb][d] = *(const bf16x8*)(Q + qoff + d * 32);
    }
    f32x4 oacc[2][8] = {};
    float mrow[2][4], lrow[2][4];
    #pragma unroll
    for (int rb = 0; rb < 2; ++rb)
        #pragma unroll
        for (int e = 0; e < 4; ++e) { mrow[rb][e] = -3.0e38f; lrow[rb][e] = 0.f; }

    int ntiles = 2 * qb + 2;
    int sr[4], ssg[4];
    bf16x8 kreg[4], vreg[4];
    #pragma unroll
    for (int c = 0; c < 4; ++c) {
        int idx = c * 256 + t;
        sr[c] = idx >> 4;             // kv row 0..63
        ssg[c] = (idx & 15) * 8;      // d offset
        size_t goff = (size_t)sr[c] * 1024 + kh * 128 + ssg[c];
        kreg[c] = *(const bf16x8*)(K + goff);
        vreg[c] = *(const bf16x8*)(V + goff);
    }
    int rowmax = q0 + w * 32 + 31;

    for (int kt = 0; kt < ntiles; ++kt) {
        int kv0 = kt * 64;
        __syncthreads();               // all waves done reading previous tile
        #pragma unroll
        for (int c = 0; c < 4; ++c) {
            *(bf16x8*)&Kl[sr[c]][ssg[c]] = kreg[c];
            u16 vv[8];
            *(bf16x8*)vv = vreg[c];
            int gsw = (sr[c] & 7) | (((sr[c] >> 3) ^ (ssg[c] >> 3)) & 7) << 3;  // note: d>>3 for d=ssg+jj
            #pragma unroll
            for (int jj = 0; jj < 8; ++jj) {
                int d = ssg[c] + jj;   // jj<8 so d>>3 == ssg[c]>>3
                Vt[d][gsw] = vv[jj];
            }
        }
        __syncthreads();
        if (kt + 1 < ntiles) {
            #pragma unroll
            for (int c = 0; c < 4; ++c) {
                size_t goff = (size_t)((kt + 1) * 64 + sr[c]) * 1024 + kh * 128 + ssg[c];
                kreg[c] = *(const bf16x8*)(K + goff);
                vreg[c] = *(const bf16x8*)(V + goff);
            }
        }
        if (kv0 <= rowmax) {
            f32x4 sacc[2][4] = {};
            #pragma unroll
            for (int cb = 0; cb < 4; ++cb)
                #pragma unroll
                for (int d = 0; d < 4; ++d) {
                    bf16x8 kf = *(const bf16x8*)&Kl[cb * 16 + lr][d * 32 + lg * 8];
                    sacc[0][cb] = __builtin_amdgcn_mfma_f32_16x16x32_bf16(qf[0][d], kf, sacc[0][cb], 0, 0, 0);
                    sacc[1][cb] = __builtin_amdgcn_mfma_f32_16x16x32_bf16(qf[1][d], kf, sacc[1][cb], 0, 0, 0);
                }
            if (kt >= 2 * qb) {       // only last two tiles can cross the diagonal
                #pragma unroll
                for (int rb = 0; rb < 2; ++rb)
                    #pragma unroll
                    for (int cb = 0; cb < 4; ++cb)
                        #pragma unroll
                        for (int e = 0; e < 4; ++e) {
                            int row = q0 + w * 32 + rb * 16 + lg * 4 + e;
                            int col = kv0 + cb * 16 + lr;
                            if (col > row) sacc[rb][cb][e] = -3.0e38f;
                        }
            }
            #pragma unroll
            for (int rb = 0; rb < 2; ++rb)
                #pragma unroll
                for (int e = 0; e < 4; ++e) {
                    float v = fmaxf(fmaxf(sacc[rb][0][e], sacc[rb][1][e]), fmaxf(sacc[rb][2][e], sacc[rb][3][e]));
                    v = fmaxf(v, __shfl_xor(v, 1));
                    v = fmaxf(v, __shfl_xor(v, 2));
                    v = fmaxf(v, __shfl_xor(v, 4));
                    v = fmaxf(v, __shfl_xor(v, 8));
                    float mnew = fmaxf(mrow[rb][e], v);
                    float alpha = exp2f((mrow[rb][e] - mnew) * cexp);
                    mrow[rb][e] = mnew;
                    float s = 0.f;
                    #pragma unroll
                    for (int cb = 0; cb < 4; ++cb) {
                        float p = exp2f((sacc[rb][cb][e] - mnew) * cexp);
                        sacc[rb][cb][e] = p;
                        s += p;
                    }
                    s += __shfl_xor(s, 1);
                    s += __shfl_xor(s, 2);
                    s += __shfl_xor(s, 4);
                    s += __shfl_xor(s, 8);
                    lrow[rb][e] = lrow[rb][e] * alpha + s;
                    #pragma unroll
                    for (int db = 0; db < 8; ++db) oacc[rb][db][e] *= alpha;
                    #pragma unroll
                    for (int cb = 0; cb < 4; ++cb)
                        Pl[w][rb * 16 + lg * 4 + e][cb * 16 + lr] = f2b(sacc[rb][cb][e]);
                }
            asm volatile("s_waitcnt lgkmcnt(0)" ::: "memory");
            __builtin_amdgcn_sched_barrier(0);
            #pragma unroll
            for (int ks = 0; ks < 2; ++ks) {
                bf16x8 pf0 = *(const bf16x8*)&Pl[w][lr][ks * 32 + lg * 8];
                bf16x8 pf1 = *(const bf16x8*)&Pl[w][16 + lr][ks * 32 + lg * 8];
                #pragma unroll
                for (int db = 0; db < 8; ++db) {
                    int vswz = (((ks * 4 + lg) ^ (db * 2 + (lr >> 3))) & 7) << 3;
                    bf16x8 vf = *(const bf16x8*)&Vt[db * 16 + lr][vswz];
                    oacc[0][db] = __builtin_amdgcn_mfma_f32_16x16x32_bf16(pf0, vf, oacc[0][db], 0, 0, 0);
                    oacc[1][db] = __builtin_amdgcn_mfma_f32_16x16x32_bf16(pf1, vf, oacc[1][db], 0, 0, 0);
                }
            }
        }
    }
    #pragma unroll
    for (int rb = 0; rb < 2; ++rb)
        #pragma unroll
        for (int db = 0; db < 8; ++db)
            #pragma unroll
            for (int e = 0; e < 4; ++e) {
                int row = q0 + w * 32 + rb * 16 + lg * 4 + e;
                O[(size_t)row * 4096 + h * 128 + db * 16 + lr] = f2b(oacc[rb][db][e] / lrow[rb][e]);
            }
}

extern "C" void kernel_launch(void* const* d_in, const int* in_sizes, int n_in,
                              void* d_out, int out_size, void* d_ws, size_t ws_size,
                              hipStream_t stream) {
    const float* hs = (const float*)d_in[0];
    const float* Wq = (const float*)d_in[1];
    const float* Wk = (const float*)d_in[2];
    const float* Wv = (const float*)d_in[3];
    const float* Wo = (const float*)d_in[4];
    float* out = (float*)d_out;
    char* ws = (char*)d_ws;
    u16* hsb = (u16*)(ws);              // 2048x4096 bf16; later reused as Ob
    u16* WqT = (u16*)(ws + 16777216);   // 4096x4096;      later reused as WoT
    u16* WkT = (u16*)(ws + 50331648);   // 1024x4096
    u16* WvT = (u16*)(ws + 58720256);   // 1024x4096
    u16* Qb  = (u16*)(ws + 67108864);   // 2048x4096
    u16* Kb  = (u16*)(ws + 83886080);   // 2048x1024
    u16* Vb  = (u16*)(ws + 88080384);   // 2048x1024

    k_cast<<<4096, 256, 0, stream>>>(hs, hsb, 2048 * 4096);
    k_transpose<<<dim3(64, 64), 256, 0, stream>>>(Wq, WqT, 4096, 4096);
    k_transpose<<<dim3(16, 64), 256, 0, stream>>>(Wk, WkT, 4096, 1024);
    k_transpose<<<dim3(16, 64), 256, 0, stream>>>(Wv, WvT, 4096, 1024);
    k_gemm_qkv<<<dim3(48, 16), 256, 0, stream>>>(hsb, WqT, WkT, WvT, Qb, Kb, Vb);
    k_rope<<<20480, 256, 0, stream>>>(Qb, Kb);
    u16* Ob = hsb;
    k_attn<<<512, 256, 0, stream>>>(Qb, Kb, Vb, Ob);
    u16* WoT = WqT;
    k_transpose<<<dim3(64, 64), 256, 0, stream>>>(Wo, WoT, 4096, 4096);
    k_gemm_out<<<dim3(32, 16), 256, 0, stream>>>(Ob, WoT, out);
}

// Round 3
// 463.799 us; speedup vs baseline: 1.5350x; 1.0426x over previous
//
#include <hip/hip_runtime.h>
#include <stdint.h>

typedef float f32x4 __attribute__((ext_vector_type(4)));
typedef __bf16 bf16x8 __attribute__((ext_vector_type(8)));
typedef unsigned short u16;
typedef unsigned short u16x8 __attribute__((ext_vector_type(8)));

__device__ __forceinline__ u16 f2b(float f) {
    union { float f; unsigned u; } v; v.f = f;
    return (u16)((v.u + 0x7fffu + ((v.u >> 16) & 1u)) >> 16);
}
__device__ __forceinline__ float b2f(u16 b) {
    union { unsigned u; float f; } v; v.u = ((unsigned)b) << 16;
    return v.f;
}

__device__ __forceinline__ void gload16(const u16* g, u16* s) {
    __builtin_amdgcn_global_load_lds((const __attribute__((address_space(1))) void*)g,
                                     (__attribute__((address_space(3))) void*)s, 16, 0, 0);
}

// ---------------- cast fp32 -> bf16 (8 elems/thread) ----------------
__global__ __launch_bounds__(256) void k_cast(const float* __restrict__ src, u16* __restrict__ dst, int n) {
    int i = (blockIdx.x * 256 + threadIdx.x) * 8;
    if (i >= n) return;
    const float4* s = (const float4*)(src + i);
    float4 a = s[0], b = s[1];
    u16x8 o;
    o[0] = f2b(a.x); o[1] = f2b(a.y); o[2] = f2b(a.z); o[3] = f2b(a.w);
    o[4] = f2b(b.x); o[5] = f2b(b.y); o[6] = f2b(b.z); o[7] = f2b(b.w);
    *(u16x8*)(dst + i) = o;
}

// ---------------- transpose + cast: src[R][C] f32 -> dst[C][R] bf16 ----------------
__global__ __launch_bounds__(256) void k_transpose(const float* __restrict__ src, u16* __restrict__ dst,
                                                   int R, int C) {
    __shared__ float tile[64][65];
    int c0 = blockIdx.x * 64, r0 = blockIdx.y * 64;
    int tx = threadIdx.x & 63, ty = threadIdx.x >> 6;
    #pragma unroll
    for (int r = ty; r < 64; r += 4)
        tile[r][tx] = src[(size_t)(r0 + r) * C + (c0 + tx)];
    __syncthreads();
    #pragma unroll
    for (int r = ty; r < 64; r += 4)
        dst[(size_t)(c0 + r) * R + (r0 + tx)] = f2b(tile[tx][r]);
}

// ============ 256x256 8-phase GEMM core (T1+T2+T3+T4+T5), BK=64, 8 waves ============
// C[m][n] = sum_k A[m][k]*Bt[n][k].  Wave grid 2M x 4N; per-wave 128x64 out (8x4 frags).
// LDS: [2 buf][2 half][128][64] for A and B (128 KiB total).
// Swizzle (involution): LDS[row][col] holds global[row][col ^ ((row&7)*8)] (elems);
// achieved by pre-swizzling the gload SOURCE col, dest stays linear (rule #21).
#define STAGE_A(h) do { \
    gload16(gA + (size_t)((h) * 128) * K + kn,     &Ah[nb][h][w * 16][0]);     \
    gload16(gA + (size_t)((h) * 128 + 8) * K + kn, &Ah[nb][h][w * 16 + 8][0]); } while (0)
#define STAGE_B(h) do { \
    gload16(gB + (size_t)((h) * 128) * K + kn,     &Bh[nb][h][w * 16][0]);     \
    gload16(gB + (size_t)((h) * 128 + 8) * K + kn, &Bh[nb][h][w * 16 + 8][0]); } while (0)
#define RD_AF(MH) do { \
    _Pragma("unroll") for (int mm = 0; mm < 4; ++mm) \
    _Pragma("unroll") for (int x = 0; x < 2; ++x) \
        af[mm][x] = *(const bf16x8*)&Ah[c][wm][((MH) * 4 + mm) * 16 + lr][(x * 32 + lk) ^ swz]; } while (0)
#define RD_BF(NH, BF) do { \
    _Pragma("unroll") for (int nn = 0; nn < 2; ++nn) \
    _Pragma("unroll") for (int x = 0; x < 2; ++x) \
        BF[nn][x] = *(const bf16x8*)&Bh[c][wn >> 1][(wn & 1) * 64 + ((NH) * 2 + nn) * 16 + lr][(x * 32 + lk) ^ swz]; } while (0)
#define MMAQ(MH, NH, BF) do { \
    _Pragma("unroll") for (int mm = 0; mm < 4; ++mm) \
    _Pragma("unroll") for (int nn = 0; nn < 2; ++nn) \
    _Pragma("unroll") for (int x = 0; x < 2; ++x) \
        acc[(MH) * 4 + mm][(NH) * 2 + nn] = __builtin_amdgcn_mfma_f32_16x16x32_bf16( \
            af[mm][x], BF[nn][x], acc[(MH) * 4 + mm][(NH) * 2 + nn], 0, 0, 0); } while (0)
#define LGKM0 do { asm volatile("s_waitcnt lgkmcnt(0)" ::: "memory"); \
                   __builtin_amdgcn_sched_barrier(0); } while (0)

template <typename OutT>
__device__ __forceinline__ void gemm256_core(const u16* __restrict__ A, const u16* __restrict__ Bt,
                                             OutT* __restrict__ C, int K, int ldc, int m0, int n0) {
    __shared__ u16 Ah[2][2][128][64];   // 64 KiB
    __shared__ u16 Bh[2][2][128][64];   // 64 KiB
    int tid = threadIdx.x;
    int l = tid & 63, w = tid >> 6;
    int wm = w >> 2, wn = w & 3;            // 2M x 4N wave grid
    int lr = l & 15, lg = l >> 4, lk = lg * 8;
    int swz = (lr & 7) << 3;                // read-side XOR (elems)
    int srow8 = l >> 3;
    int scol = ((l & 7) ^ srow8) * 8;       // pre-swizzled source col (elems)
    const u16* gA = A  + (size_t)(m0 + w * 16 + srow8) * K + scol;
    const u16* gB = Bt + (size_t)(n0 + w * 16 + srow8) * K + scol;
    f32x4 acc[8][4] = {};
    int NT = K >> 6;

    {   // prologue: stage tile 0 into buf 0 (8 loads/thread)
        int kn = 0, nb = 0;
        STAGE_A(0); STAGE_A(1); STAGE_B(0); STAGE_B(1);
    }

    #pragma unroll 2
    for (int t = 0; t < NT; ++t) {
        int c = t & 1, nb = c ^ 1;
        int kn = (t + 1) << 6;
        bool last = (t == NT - 1);
        bf16x8 af[4][2], bf0[2][2], bf1[2][2];
        // ---- phase 0: quadrant (0,0); stage A-half0(t+1); validate buf c ----
        if (!last) {
            STAGE_A(0);
            asm volatile("s_waitcnt vmcnt(2)" ::: "memory");   // tile t's 8 loads done
        } else {
            asm volatile("s_waitcnt vmcnt(0)" ::: "memory");
        }
        __builtin_amdgcn_s_barrier();
        RD_AF(0); RD_BF(0, bf0);
        LGKM0;
        __builtin_amdgcn_s_setprio(1);
        MMAQ(0, 0, bf0);
        __builtin_amdgcn_s_setprio(0);
        __builtin_amdgcn_s_barrier();
        // ---- phase 1: quadrant (0,1); stage A-half1(t+1) ----
        if (!last) STAGE_A(1);
        RD_BF(1, bf1);
        __builtin_amdgcn_s_barrier();
        LGKM0;
        __builtin_amdgcn_s_setprio(1);
        MMAQ(0, 1, bf1);
        __builtin_amdgcn_s_setprio(0);
        __builtin_amdgcn_s_barrier();
        // ---- phase 2: quadrant (1,1); stage B-half0(t+1) ----
        if (!last) STAGE_B(0);
        RD_AF(1);
        __builtin_amdgcn_s_barrier();
        LGKM0;
        __builtin_amdgcn_s_setprio(1);
        MMAQ(1, 1, bf1);
        __builtin_amdgcn_s_setprio(0);
        __builtin_amdgcn_s_barrier();
        // ---- phase 3: quadrant (1,0); stage B-half1(t+1); reuses af+bf0 ----
        if (!last) STAGE_B(1);
        __builtin_amdgcn_s_barrier();
        __builtin_amdgcn_s_setprio(1);
        MMAQ(1, 0, bf0);
        __builtin_amdgcn_s_setprio(0);
        __builtin_amdgcn_s_barrier();
    }

    #pragma unroll
    for (int m = 0; m < 8; ++m)
        #pragma unroll
        for (int n = 0; n < 4; ++n)
            #pragma unroll
            for (int e = 0; e < 4; ++e) {
                int row = m0 + wm * 128 + m * 16 + lg * 4 + e;
                int col = n0 + wn * 64 + n * 16 + lr;
                if constexpr (sizeof(OutT) == 4)
                    C[(size_t)row * ldc + col] = acc[m][n][e];
                else
                    C[(size_t)row * ldc + col] = f2b(acc[m][n][e]);
            }
}

// QKV fused: N = 6144 = 16 Q-tiles + 4 K-tiles + 4 V-tiles of 256. Grid 192 (8 m x 24 n).
__global__ __launch_bounds__(512, 2) void k_gemm_qkv(const u16* __restrict__ hsb,
        const u16* __restrict__ WqT, const u16* __restrict__ WkT, const u16* __restrict__ WvT,
        u16* __restrict__ Qb, u16* __restrict__ Kb, u16* __restrict__ Vb) {
    int bid = blockIdx.x;
    int ord = (bid & 7) * 24 + (bid >> 3);   // XCD swizzle (192 % 8 == 0)
    int mt = ord / 24, nt = ord % 24;
    const u16* Bt; u16* Cd; int ldc, n0;
    if (nt < 16)      { Bt = WqT; Cd = Qb; ldc = 4096; n0 = nt * 256; }
    else if (nt < 20) { Bt = WkT; Cd = Kb; ldc = 1024; n0 = (nt - 16) * 256; }
    else              { Bt = WvT; Cd = Vb; ldc = 1024; n0 = (nt - 20) * 256; }
    gemm256_core<u16>(hsb, Bt, Cd, 4096, ldc, mt * 256, n0);
}

// Out-proj: grid 128 (8 m x 16 n), fp32 output.
__global__ __launch_bounds__(512, 2) void k_gemm_out(const u16* __restrict__ Ob, const u16* __restrict__ WoT,
                                                     float* __restrict__ out) {
    int bid = blockIdx.x;
    int ord = (bid & 7) * 16 + (bid >> 3);   // XCD swizzle (128 % 8 == 0)
    int mt = ord >> 4, nt = ord & 15;
    gemm256_core<float>(Ob, WoT, out, 4096, 4096, mt * 256, nt * 256);
}

// ---------------- RoPE in-place on Q (32 heads) and K (8 heads) ----------------
__global__ __launch_bounds__(256) void k_rope(u16* __restrict__ Qb, u16* __restrict__ Kb) {
    int t = blockIdx.x * 256 + threadIdx.x;
    int i = t & 63;
    int rest = t >> 6;
    int head = rest % 40;
    int s = rest / 40;
    if (s >= 2048) return;
    u16* base = (head < 32) ? (Qb + (size_t)s * 4096 + head * 128)
                            : (Kb + (size_t)s * 1024 + (head - 32) * 128);
    float inv = exp2f((float)i * (-13.287712379549449f / 64.0f));
    float fr = (float)s * inv;
    float sn, cs;
    sincosf(fr, &sn, &cs);
    float x1 = b2f(base[i]), x2 = b2f(base[i + 64]);
    base[i]      = f2b(x1 * cs - x2 * sn);
    base[i + 64] = f2b(x2 * cs + x1 * sn);
}

// ---------------- Flash attention, causal, GQA 32/8, Dh=128 ----------------
__global__ __launch_bounds__(256, 2) void k_attn(const u16* __restrict__ Q, const u16* __restrict__ K,
                                                 const u16* __restrict__ V, u16* __restrict__ O) {
    __shared__ u16 Kl[64][136];    // [kv][d], +8 pad
    __shared__ u16 Vt[128][72];    // [d][kv swizzled], +8 pad
    __shared__ u16 Pl[4][32][72];  // per-wave P [qrow32][kv64], +8 pad
    int bid = blockIdx.x;
    int h = bid & 31;
    int j = bid >> 5;
    int qb = (j < 8) ? j : 23 - j;
    int kh = h >> 2;
    int q0 = qb * 128;
    int t = threadIdx.x, l = t & 63, w = t >> 6;
    int lr = l & 15, lg = l >> 4;
    const float cexp = 0.12751742f;  // log2(e)/sqrt(128)

    bf16x8 qf[2][4];
    #pragma unroll
    for (int rb = 0; rb < 2; ++rb) {
        size_t qoff = (size_t)(q0 + w * 32 + rb * 16 + lr) * 4096 + h * 128 + lg * 8;
        #pragma unroll
        for (int d = 0; d < 4; ++d)
            qf[rb][d] = *(const bf16x8*)(Q + qoff + d * 32);
    }
    f32x4 oacc[2][8] = {};
    float mrow[2][4], lrow[2][4];
    #pragma unroll
    for (int rb = 0; rb < 2; ++rb)
        #pragma unroll
        for (int e = 0; e < 4; ++e) { mrow[rb][e] = -3.0e38f; lrow[rb][e] = 0.f; }

    int ntiles = 2 * qb + 2;
    int sr[4], ssg[4];
    bf16x8 kreg[4], vreg[4];
    #pragma unroll
    for (int c = 0; c < 4; ++c) {
        int idx = c * 256 + t;
        sr[c] = idx >> 4;
        ssg[c] = (idx & 15) * 8;
        size_t goff = (size_t)sr[c] * 1024 + kh * 128 + ssg[c];
        kreg[c] = *(const bf16x8*)(K + goff);
        vreg[c] = *(const bf16x8*)(V + goff);
    }
    int rowmax = q0 + w * 32 + 31;

    for (int kt = 0; kt < ntiles; ++kt) {
        int kv0 = kt * 64;
        __syncthreads();
        #pragma unroll
        for (int c = 0; c < 4; ++c) {
            *(bf16x8*)&Kl[sr[c]][ssg[c]] = kreg[c];
            u16 vv[8];
            *(bf16x8*)vv = vreg[c];
            int gsw = (sr[c] & 7) | (((sr[c] >> 3) ^ (ssg[c] >> 3)) & 7) << 3;
            #pragma unroll
            for (int jj = 0; jj < 8; ++jj) {
                int d = ssg[c] + jj;
                Vt[d][gsw] = vv[jj];
            }
        }
        __syncthreads();
        if (kt + 1 < ntiles) {
            #pragma unroll
            for (int c = 0; c < 4; ++c) {
                size_t goff = (size_t)((kt + 1) * 64 + sr[c]) * 1024 + kh * 128 + ssg[c];
                kreg[c] = *(const bf16x8*)(K + goff);
                vreg[c] = *(const bf16x8*)(V + goff);
            }
        }
        if (kv0 <= rowmax) {
            f32x4 sacc[2][4] = {};
            #pragma unroll
            for (int cb = 0; cb < 4; ++cb)
                #pragma unroll
                for (int d = 0; d < 4; ++d) {
                    bf16x8 kf = *(const bf16x8*)&Kl[cb * 16 + lr][d * 32 + lg * 8];
                    sacc[0][cb] = __builtin_amdgcn_mfma_f32_16x16x32_bf16(qf[0][d], kf, sacc[0][cb], 0, 0, 0);
                    sacc[1][cb] = __builtin_amdgcn_mfma_f32_16x16x32_bf16(qf[1][d], kf, sacc[1][cb], 0, 0, 0);
                }
            if (kt >= 2 * qb) {
                #pragma unroll
                for (int rb = 0; rb < 2; ++rb)
                    #pragma unroll
                    for (int cb = 0; cb < 4; ++cb)
                        #pragma unroll
                        for (int e = 0; e < 4; ++e) {
                            int row = q0 + w * 32 + rb * 16 + lg * 4 + e;
                            int col = kv0 + cb * 16 + lr;
                            if (col > row) sacc[rb][cb][e] = -3.0e38f;
                        }
            }
            #pragma unroll
            for (int rb = 0; rb < 2; ++rb)
                #pragma unroll
                for (int e = 0; e < 4; ++e) {
                    float v = fmaxf(fmaxf(sacc[rb][0][e], sacc[rb][1][e]), fmaxf(sacc[rb][2][e], sacc[rb][3][e]));
                    v = fmaxf(v, __shfl_xor(v, 1));
                    v = fmaxf(v, __shfl_xor(v, 2));
                    v = fmaxf(v, __shfl_xor(v, 4));
                    v = fmaxf(v, __shfl_xor(v, 8));
                    float mnew = fmaxf(mrow[rb][e], v);
                    float alpha = exp2f((mrow[rb][e] - mnew) * cexp);
                    mrow[rb][e] = mnew;
                    float s = 0.f;
                    #pragma unroll
                    for (int cb = 0; cb < 4; ++cb) {
                        float p = exp2f((sacc[rb][cb][e] - mnew) * cexp);
                        sacc[rb][cb][e] = p;
                        s += p;
                    }
                    s += __shfl_xor(s, 1);
                    s += __shfl_xor(s, 2);
                    s += __shfl_xor(s, 4);
                    s += __shfl_xor(s, 8);
                    lrow[rb][e] = lrow[rb][e] * alpha + s;
                    #pragma unroll
                    for (int db = 0; db < 8; ++db) oacc[rb][db][e] *= alpha;
                    #pragma unroll
                    for (int cb = 0; cb < 4; ++cb)
                        Pl[w][rb * 16 + lg * 4 + e][cb * 16 + lr] = f2b(sacc[rb][cb][e]);
                }
            asm volatile("s_waitcnt lgkmcnt(0)" ::: "memory");
            __builtin_amdgcn_sched_barrier(0);
            #pragma unroll
            for (int ks = 0; ks < 2; ++ks) {
                bf16x8 pf0 = *(const bf16x8*)&Pl[w][lr][ks * 32 + lg * 8];
                bf16x8 pf1 = *(const bf16x8*)&Pl[w][16 + lr][ks * 32 + lg * 8];
                #pragma unroll
                for (int db = 0; db < 8; ++db) {
                    int vswz = (((ks * 4 + lg) ^ (db * 2 + (lr >> 3))) & 7) << 3;
                    bf16x8 vf = *(const bf16x8*)&Vt[db * 16 + lr][vswz];
                    oacc[0][db] = __builtin_amdgcn_mfma_f32_16x16x32_bf16(pf0, vf, oacc[0][db], 0, 0, 0);
                    oacc[1][db] = __builtin_amdgcn_mfma_f32_16x16x32_bf16(pf1, vf, oacc[1][db], 0, 0, 0);
                }
            }
        }
    }
    #pragma unroll
    for (int rb = 0; rb < 2; ++rb)
        #pragma unroll
        for (int db = 0; db < 8; ++db)
            #pragma unroll
            for (int e = 0; e < 4; ++e) {
                int row = q0 + w * 32 + rb * 16 + lg * 4 + e;
                O[(size_t)row * 4096 + h * 128 + db * 16 + lr] = f2b(oacc[rb][db][e] / lrow[rb][e]);
            }
}

extern "C" void kernel_launch(void* const* d_in, const int* in_sizes, int n_in,
                              void* d_out, int out_size, void* d_ws, size_t ws_size,
                              hipStream_t stream) {
    const float* hs = (const float*)d_in[0];
    const float* Wq = (const float*)d_in[1];
    const float* Wk = (const float*)d_in[2];
    const float* Wv = (const float*)d_in[3];
    const float* Wo = (const float*)d_in[4];
    float* out = (float*)d_out;
    char* ws = (char*)d_ws;
    u16* hsb = (u16*)(ws);              // 2048x4096 bf16; later reused as Ob
    u16* WqT = (u16*)(ws + 16777216);   // 4096x4096;      later reused as WoT
    u16* WkT = (u16*)(ws + 50331648);   // 1024x4096
    u16* WvT = (u16*)(ws + 58720256);   // 1024x4096
    u16* Qb  = (u16*)(ws + 67108864);   // 2048x4096
    u16* Kb  = (u16*)(ws + 83886080);   // 2048x1024
    u16* Vb  = (u16*)(ws + 88080384);   // 2048x1024

    k_cast<<<4096, 256, 0, stream>>>(hs, hsb, 2048 * 4096);
    k_transpose<<<dim3(64, 64), 256, 0, stream>>>(Wq, WqT, 4096, 4096);
    k_transpose<<<dim3(16, 64), 256, 0, stream>>>(Wk, WkT, 4096, 1024);
    k_transpose<<<dim3(16, 64), 256, 0, stream>>>(Wv, WvT, 4096, 1024);
    k_gemm_qkv<<<192, 512, 0, stream>>>(hsb, WqT, WkT, WvT, Qb, Kb, Vb);
    k_rope<<<20480, 256, 0, stream>>>(Qb, Kb);
    u16* Ob = hsb;
    k_attn<<<512, 256, 0, stream>>>(Qb, Kb, Vb, Ob);
    u16* WoT = WqT;
    k_transpose<<<dim3(64, 64), 256, 0, stream>>>(Wo, WoT, 4096, 4096);
    k_gemm_out<<<128, 512, 0, stream>>>(Ob, WoT, out);
}